// Round 10
// baseline (640.492 us; speedup 1.0000x reference)
//
#include <hip/hip_runtime.h>
#include <hip/hip_cooperative_groups.h>
namespace cg = cooperative_groups;

#define NN 100000
#define NE 1600000
#define NPB 128                       // nodes per coarse bucket (node>>7)
#define NBUCK ((NN + NPB - 1) / NPB)  // 782
#define NSB 512                       // scatter blocks / hist chunks
#define ESB (NE / NSB)                // 3125 edges per chunk
#define PCAP 3072                     // LDS staging cap in place (bucket avg ~2046)
#define NGRID 512                     // cooperative grid size
// IN_C = HID_C = 64, OUT_C = 16

typedef __bf16 v8bf __attribute__((ext_vector_type(8)));
typedef float  v4f  __attribute__((ext_vector_type(4)));

union Frag { v8bf v; uint4 u; unsigned short s[8]; };

struct Params {
    const int* src; const int* dst; const float* x;
    const float* W1; const float* W2;
    const float* b1; const float* b2;
    const float* Wfc; const float* bfc;
    float* out;
    int* histT; int* baseT; int* btot; int* bucket_start; int* counter;
    int* deg; float* dinv; int* row_start; int* srt;
    unsigned* bufA; unsigned* bufC; int* pairs;
    unsigned short* Wp1; unsigned short* Wp2;
};

union Smem {
    int lhist[NBUCK];                 // hist
    int sd[256];                      // colscan / bscan
    int lcur[NBUCK];                  // scatter
    struct {
        int lp[PCAP];
        int lcnt[NPB]; int loff[NPB]; int lpos[NPB]; int sd2[NPB];
        float ldinv[NPB];
    } pl;                             // place (+gemm1)   -> 14848 B max
    unsigned short hsl[64][72];       // agg1+gemm2 (9216 B)
    struct { float Ws[64][16]; float hs[16][68]; } fc;   // agg2+final (8448 B)
};

__device__ inline unsigned f2bf(float f) {
    unsigned u = __float_as_uint(f);
    return (u + 0x7fffu + ((u >> 16) & 1u)) >> 16;
}

__device__ inline float4 bf4_to_f4(uint2 u) {
    float4 r;
    r.x = __uint_as_float(u.x << 16);
    r.y = __uint_as_float(u.x & 0xffff0000u);
    r.z = __uint_as_float(u.y << 16);
    r.w = __uint_as_float(u.y & 0xffff0000u);
    return r;
}

// ---------------- P0: hist (all blocks) + wpack (blocks 0,1) + ctr (block 2) --
__device__ void phase_hist(const Params& P, Smem& S) {
    int t = threadIdx.x, b = blockIdx.x;
    for (int i = t; i < NBUCK; i += 256) S.lhist[i] = 0;
    __syncthreads();
    int start = b * ESB, end = start + ESB;
    for (int e = start + t; e < end; e += 256)
        atomicAdd(&S.lhist[P.dst[e] >> 7], 1);
    __syncthreads();
    for (int i = t; i < NBUCK; i += 256)
        P.histT[i * NSB + b] = S.lhist[i];           // bucket-major
    if (b < 2) {
        const float* W = b ? P.W2 : P.W1;
        unsigned short* Wp = b ? P.Wp2 : P.Wp1;
        for (int idx = t; idx < 4096; idx += 256) {
            int j = idx & 7, n = (idx >> 3) & 15, f = idx >> 7;
            int q = f & 3, s = (f >> 2) & 1, c = f >> 3;
            Wp[idx] = (unsigned short)f2bf(W[(32 * s + 8 * q + j) * 64 + 16 * c + n]);
        }
    }
    if (b == 2 && t == 0) atomicExch(P.counter, 0);
}

// ---------------- P1: per-bucket colscan; last-finishing block does bscan -----
__device__ void phase_colscan(const Params& P, Smem& S) {
    int t = threadIdx.x, b = blockIdx.x;
    for (int k = b; k < NBUCK; k += NGRID) {
        __syncthreads();
        const int* col = P.histT + k * NSB;
        int a0 = col[2 * t], a1 = col[2 * t + 1];
        int my = a0 + a1;
        S.sd[t] = my;
        __syncthreads();
        #pragma unroll
        for (int off = 1; off < 256; off <<= 1) {
            int v = (t >= off) ? S.sd[t - off] : 0;
            __syncthreads();
            S.sd[t] += v;
            __syncthreads();
        }
        int excl = S.sd[t] - my;
        P.baseT[k * NSB + 2 * t]     = excl;
        P.baseT[k * NSB + 2 * t + 1] = excl + a0;
        if (t == 255) atomicExch(&P.btot[k], S.sd[255]);   // device-scope publish
    }
    __syncthreads();
    if (t == 0) S.sd[0] = (atomicAdd(P.counter, 1) == NGRID - 1) ? 1 : 0;
    __syncthreads();
    int last = S.sd[0];
    __syncthreads();
    if (!last) return;
    // ---- bscan by the last-arriving block ----
    __threadfence();
    int base = t * 4;
    int d0 = (base + 0 < NBUCK) ? atomicAdd(&P.btot[base + 0], 0) : 0;
    int d1 = (base + 1 < NBUCK) ? atomicAdd(&P.btot[base + 1], 0) : 0;
    int d2 = (base + 2 < NBUCK) ? atomicAdd(&P.btot[base + 2], 0) : 0;
    int d3 = (base + 3 < NBUCK) ? atomicAdd(&P.btot[base + 3], 0) : 0;
    int m2 = d0 + d1 + d2 + d3;
    __syncthreads();
    S.sd[t] = m2;
    __syncthreads();
    #pragma unroll
    for (int off = 1; off < 256; off <<= 1) {
        int v = (t >= off) ? S.sd[t - off] : 0;
        __syncthreads();
        S.sd[t] += v;
        __syncthreads();
    }
    int ex2 = S.sd[t] - m2;
    if (base + 0 < NBUCK) P.bucket_start[base + 0] = ex2;
    if (base + 1 < NBUCK) P.bucket_start[base + 1] = ex2 + d0;
    if (base + 2 < NBUCK) P.bucket_start[base + 2] = ex2 + d0 + d1;
    if (base + 3 < NBUCK) P.bucket_start[base + 3] = ex2 + d0 + d1 + d2;
    if (t == 255) P.bucket_start[NBUCK] = S.sd[255];   // == NE
}

// ---------------- P2: stable bucket scatter, packed payload -------------------
__device__ void phase_scatter(const Params& P, Smem& S) {
    int t = threadIdx.x, b = blockIdx.x;
    for (int i = t; i < NBUCK; i += 256)
        S.lcur[i] = P.bucket_start[i] + P.baseT[i * NSB + b];
    __syncthreads();
    int start = b * ESB, end = start + ESB;
    for (int e = start + t; e < end; e += 256) {
        int d = P.dst[e];
        int pos = atomicAdd(&S.lcur[d >> 7], 1);
        P.pairs[pos] = ((d & 127) << 20) | P.src[e];
    }
}

// ---------------- P3: deg/dinv/row_start + CSR placement + layer-1 gemm ------
__device__ void phase_place(const Params& P, Smem& S) {
    int t = threadIdx.x, b = blockIdx.x;
    int lane = t & 63, wv = t >> 6;
    int m = lane & 15, quad = lane >> 4;
    for (int k = b; k < NBUCK; k += NGRID) {
        __syncthreads();
        if (t < NPB) { S.pl.lcnt[t] = 0; S.pl.lpos[t] = 0; }
        __syncthreads();
        int bs = P.bucket_start[k], be = P.bucket_start[k + 1];
        int n = be - bs;
        int node0 = k * NPB;
        for (int pos = t; pos < n; pos += 256) {
            int p = P.pairs[bs + pos];
            if (pos < PCAP) S.pl.lp[pos] = p;
            atomicAdd(&S.pl.lcnt[p >> 20], 1);
        }
        __syncthreads();
        int my = (t < NPB) ? S.pl.lcnt[t] : 0;
        if (t < NPB) S.pl.sd2[t] = my;
        __syncthreads();
        #pragma unroll
        for (int off = 1; off < NPB; off <<= 1) {
            int v = (t < NPB && t >= off) ? S.pl.sd2[t - off] : 0;
            __syncthreads();
            if (t < NPB) S.pl.sd2[t] += v;
            __syncthreads();
        }
        if (t < NPB) {
            int excl = S.pl.sd2[t] - my;
            S.pl.loff[t] = excl;
            float dv = rsqrtf((float)(my + 1));
            S.pl.ldinv[t] = dv;
            int nd = node0 + t;
            if (nd < NN) {
                P.deg[nd] = my;
                P.dinv[nd] = dv;
                P.row_start[nd] = bs + excl;
            }
        }
        __syncthreads();
        for (int pos = t; pos < n; pos += 256) {
            int p = (pos < PCAP) ? S.pl.lp[pos] : P.pairs[bs + pos];
            int loc = p >> 20;
            int off = atomicAdd(&S.pl.lpos[loc], 1);
            P.srt[bs + S.pl.loff[loc] + off] = p & 0xFFFFF;
        }
        // layer-1 gemm for this bucket's 128 nodes (2 tiles per wave)
        Frag bfr[8];
        #pragma unroll
        for (int cs = 0; cs < 8; ++cs)
            bfr[cs].u = *(const uint4*)(P.Wp1 + ((cs * 4 + quad) * 16 + m) * 8);
        #pragma unroll
        for (int tt = 0; tt < 2; ++tt) {
            int tnode0 = node0 + (wv * 2 + tt) * 16;
            int node = tnode0 + m;
            int ln = (node < NN) ? node : NN - 1;
            Frag a[2];
            const float* xr = P.x + ln * 64 + quad * 8;
            #pragma unroll
            for (int s = 0; s < 2; ++s) {
                float4 f0 = *(const float4*)(xr + s * 32);
                float4 f1 = *(const float4*)(xr + s * 32 + 4);
                a[s].s[0] = (unsigned short)f2bf(f0.x);
                a[s].s[1] = (unsigned short)f2bf(f0.y);
                a[s].s[2] = (unsigned short)f2bf(f0.z);
                a[s].s[3] = (unsigned short)f2bf(f0.w);
                a[s].s[4] = (unsigned short)f2bf(f1.x);
                a[s].s[5] = (unsigned short)f2bf(f1.y);
                a[s].s[6] = (unsigned short)f2bf(f1.z);
                a[s].s[7] = (unsigned short)f2bf(f1.w);
            }
            v4f acc[4] = {};
            #pragma unroll
            for (int c = 0; c < 4; ++c) {
                acc[c] = __builtin_amdgcn_mfma_f32_16x16x32_bf16(a[0].v, bfr[c * 2 + 0].v, acc[c], 0, 0, 0);
                acc[c] = __builtin_amdgcn_mfma_f32_16x16x32_bf16(a[1].v, bfr[c * 2 + 1].v, acc[c], 0, 0, 0);
            }
            #pragma unroll
            for (int r = 0; r < 4; ++r) {
                int onode = tnode0 + quad * 4 + r;
                float di = S.pl.ldinv[(onode - node0) & (NPB - 1)];
                #pragma unroll
                for (int c = 0; c < 4; ++c) {
                    float v = acc[c][r] * di;
                    float p = __shfl_xor(v, 1);
                    if (!(lane & 1) && onode < NN) {
                        unsigned pk = f2bf(v) | (f2bf(p) << 16);
                        P.bufA[onode * 32 + c * 8 + (m >> 1)] = pk;
                    }
                }
            }
        }
    }
}

// ---------------- shared gather core (R7 8/4/1 ladder) -----------------------
__device__ inline float4 gather_row(const int* __restrict__ row_start,
                                    const int* __restrict__ deg,
                                    const int* __restrict__ sorted_src,
                                    const uint2* __restrict__ hb,
                                    const float* __restrict__ dinv,
                                    const float* __restrict__ b,
                                    int node, int q) {
    int e = row_start[node];
    int end = e + deg[node];
    float4 acc = bf4_to_f4(hb[node * 16 + q]);   // self-loop term
    while (e < end) {
        int take = min(end - e, 16);
        int sidx = (q < take) ? sorted_src[e + q] : 0;
        int j = 0;
        for (; j + 8 <= take; j += 8) {
            int s0 = __shfl(sidx, j + 0, 16);
            int s1 = __shfl(sidx, j + 1, 16);
            int s2 = __shfl(sidx, j + 2, 16);
            int s3 = __shfl(sidx, j + 3, 16);
            int s4 = __shfl(sidx, j + 4, 16);
            int s5 = __shfl(sidx, j + 5, 16);
            int s6 = __shfl(sidx, j + 6, 16);
            int s7 = __shfl(sidx, j + 7, 16);
            uint2 u0 = hb[s0 * 16 + q];
            uint2 u1 = hb[s1 * 16 + q];
            uint2 u2 = hb[s2 * 16 + q];
            uint2 u3 = hb[s3 * 16 + q];
            uint2 u4 = hb[s4 * 16 + q];
            uint2 u5 = hb[s5 * 16 + q];
            uint2 u6 = hb[s6 * 16 + q];
            uint2 u7 = hb[s7 * 16 + q];
            float4 v0 = bf4_to_f4(u0), v1 = bf4_to_f4(u1);
            float4 v2 = bf4_to_f4(u2), v3 = bf4_to_f4(u3);
            float4 v4 = bf4_to_f4(u4), v5 = bf4_to_f4(u5);
            float4 v6 = bf4_to_f4(u6), v7 = bf4_to_f4(u7);
            acc.x += (v0.x + v1.x) + (v2.x + v3.x) + (v4.x + v5.x) + (v6.x + v7.x);
            acc.y += (v0.y + v1.y) + (v2.y + v3.y) + (v4.y + v5.y) + (v6.y + v7.y);
            acc.z += (v0.z + v1.z) + (v2.z + v3.z) + (v4.z + v5.z) + (v6.z + v7.z);
            acc.w += (v0.w + v1.w) + (v2.w + v3.w) + (v4.w + v5.w) + (v6.w + v7.w);
        }
        for (; j + 4 <= take; j += 4) {
            int s0 = __shfl(sidx, j + 0, 16);
            int s1 = __shfl(sidx, j + 1, 16);
            int s2 = __shfl(sidx, j + 2, 16);
            int s3 = __shfl(sidx, j + 3, 16);
            uint2 u0 = hb[s0 * 16 + q];
            uint2 u1 = hb[s1 * 16 + q];
            uint2 u2 = hb[s2 * 16 + q];
            uint2 u3 = hb[s3 * 16 + q];
            float4 v0 = bf4_to_f4(u0), v1 = bf4_to_f4(u1);
            float4 v2 = bf4_to_f4(u2), v3 = bf4_to_f4(u3);
            acc.x += (v0.x + v1.x) + (v2.x + v3.x);
            acc.y += (v0.y + v1.y) + (v2.y + v3.y);
            acc.z += (v0.z + v1.z) + (v2.z + v3.z);
            acc.w += (v0.w + v1.w) + (v2.w + v3.w);
        }
        for (; j < take; ++j) {
            int s0 = __shfl(sidx, j, 16);
            float4 v0 = bf4_to_f4(hb[s0 * 16 + q]);
            acc.x += v0.x; acc.y += v0.y; acc.z += v0.z; acc.w += v0.w;
        }
        e += take;
    }
    float di = dinv[node];
    float4 bb = *(const float4*)(b + q * 4);
    float4 r;
    r.x = fmaxf(fmaf(di, acc.x, bb.x), 0.f);
    r.y = fmaxf(fmaf(di, acc.y, bb.y), 0.f);
    r.z = fmaxf(fmaf(di, acc.z, bb.z), 0.f);
    r.w = fmaxf(fmaf(di, acc.w, bb.w), 0.f);
    return r;
}

// ---------------- P4: layer-1 aggregate -> LDS -> layer-2 gemm ---------------
__device__ void phase_agg1(const Params& P, Smem& S) {
    int t = threadIdx.x;
    int lane = t & 63, wv = t >> 6;
    int q = lane & 15;
    int m = lane & 15, quad = lane >> 4;
    for (int g = blockIdx.x; g < (NN + 63) / 64; g += NGRID) {
        int node0 = g * 64;
        __syncthreads();   // protect hsl from previous iteration's readers
        #pragma unroll
        for (int r4 = 0; r4 < 4; ++r4) {
            int nl = wv * 16 + r4 * 4 + (lane >> 4);
            int node = node0 + nl;
            int cn = (node < NN) ? node : NN - 1;
            float4 r = gather_row(P.row_start, P.deg, P.srt, (const uint2*)P.bufA,
                                  P.dinv, P.b1, cn, q);
            uint2 pk;
            pk.x = f2bf(r.x) | (f2bf(r.y) << 16);
            pk.y = f2bf(r.z) | (f2bf(r.w) << 16);
            *(uint2*)&S.hsl[nl][q * 4] = pk;
        }
        __syncthreads();
        Frag b[8];
        #pragma unroll
        for (int cs = 0; cs < 8; ++cs)
            b[cs].u = *(const uint4*)(P.Wp2 + ((cs * 4 + quad) * 16 + m) * 8);
        Frag a[2];
        #pragma unroll
        for (int s = 0; s < 2; ++s)
            a[s].u = *(const uint4*)&S.hsl[wv * 16 + m][s * 32 + quad * 8];
        v4f acc[4] = {};
        #pragma unroll
        for (int c = 0; c < 4; ++c) {
            acc[c] = __builtin_amdgcn_mfma_f32_16x16x32_bf16(a[0].v, b[c * 2 + 0].v, acc[c], 0, 0, 0);
            acc[c] = __builtin_amdgcn_mfma_f32_16x16x32_bf16(a[1].v, b[c * 2 + 1].v, acc[c], 0, 0, 0);
        }
        #pragma unroll
        for (int r = 0; r < 4; ++r) {
            int onode = node0 + wv * 16 + quad * 4 + r;
            float di = P.dinv[(onode < NN) ? onode : NN - 1];
            #pragma unroll
            for (int c = 0; c < 4; ++c) {
                float v = acc[c][r] * di;
                float p = __shfl_xor(v, 1);
                if (!(lane & 1) && onode < NN) {
                    unsigned pk = f2bf(v) | (f2bf(p) << 16);
                    P.bufC[onode * 32 + c * 8 + (m >> 1)] = pk;
                }
            }
        }
    }
}

// ---------------- P5: layer-2 aggregate + FC + log_softmax -------------------
__device__ void phase_agg2(const Params& P, Smem& S) {
    int t = threadIdx.x;
    #pragma unroll
    for (int k = 0; k < 4; ++k)
        ((float*)S.fc.Ws)[k * 256 + t] = P.Wfc[k * 256 + t];
    for (int g = blockIdx.x; g < NN * 16 / 256; g += NGRID) {
        __syncthreads();   // Ws visible; hs safe from previous iteration
        int node = g * 16 + (t >> 4);
        int q = t & 15;
        float4 r = gather_row(P.row_start, P.deg, P.srt, (const uint2*)P.bufC,
                              P.dinv, P.b2, node, q);
        S.fc.hs[t >> 4][q * 4 + 0] = r.x;
        S.fc.hs[t >> 4][q * 4 + 1] = r.y;
        S.fc.hs[t >> 4][q * 4 + 2] = r.z;
        S.fc.hs[t >> 4][q * 4 + 3] = r.w;
        __syncthreads();
        int nl = t >> 4;
        int c  = t & 15;
        float acc = P.bfc[c];
        #pragma unroll
        for (int k = 0; k < 64; ++k)
            acc = fmaf(S.fc.hs[nl][k], S.fc.Ws[k][c], acc);
        float m = acc;
        #pragma unroll
        for (int off = 8; off; off >>= 1)
            m = fmaxf(m, __shfl_xor(m, off, 16));
        float ex = __expf(acc - m);
        float s = ex;
        #pragma unroll
        for (int off = 8; off; off >>= 1)
            s += __shfl_xor(s, off, 16);
        P.out[g * 256 + t] = acc - m - __logf(s);
    }
}

// ---------------- cooperative mega-kernel ------------------------------------
__global__ __launch_bounds__(256, 4) void gcn_mega(Params P) {
    __shared__ Smem S;
    cg::grid_group grid = cg::this_grid();
    phase_hist(P, S);      grid.sync();
    phase_colscan(P, S);   grid.sync();
    phase_scatter(P, S);   grid.sync();
    phase_place(P, S);     grid.sync();
    phase_agg1(P, S);      grid.sync();
    phase_agg2(P, S);
}

// ---------------- fallback: same phases as plain kernels ---------------------
__global__ __launch_bounds__(256, 4) void k_hist(Params P)    { __shared__ Smem S; phase_hist(P, S); }
__global__ __launch_bounds__(256, 4) void k_colscan(Params P) { __shared__ Smem S; phase_colscan(P, S); }
__global__ __launch_bounds__(256, 4) void k_scatter(Params P) { __shared__ Smem S; phase_scatter(P, S); }
__global__ __launch_bounds__(256, 4) void k_place(Params P)   { __shared__ Smem S; phase_place(P, S); }
__global__ __launch_bounds__(256, 4) void k_agg1(Params P)    { __shared__ Smem S; phase_agg1(P, S); }
__global__ __launch_bounds__(256, 4) void k_agg2(Params P)    { __shared__ Smem S; phase_agg2(P, S); }

extern "C" void kernel_launch(void* const* d_in, const int* in_sizes, int n_in,
                              void* d_out, int out_size, void* d_ws, size_t ws_size,
                              hipStream_t stream) {
    const float* x   = (const float*)d_in[0];
    const int*   ei  = (const int*)d_in[1];     // [2, E] int32
    const float* W1  = (const float*)d_in[2];
    const float* b1  = (const float*)d_in[3];
    const float* W2  = (const float*)d_in[4];
    const float* b2  = (const float*)d_in[5];
    const float* Wfc = (const float*)d_in[6];
    const float* bfc = (const float*)d_in[7];

    char* ws = (char*)d_ws;
    Params P;
    P.src = ei;                                  // edge_index[0]
    P.dst = ei + NE;                             // edge_index[1]
    P.x = x; P.W1 = W1; P.W2 = W2; P.b1 = b1; P.b2 = b2; P.Wfc = Wfc; P.bfc = bfc;
    P.out = (float*)d_out;
    P.deg          = (int*)(ws + 0);             // 400 KB
    P.dinv         = (float*)(ws + 524288);      // 400 KB
    P.row_start    = (int*)(ws + 1048576);       // 400 KB
    P.btot         = (int*)(ws + 1572864);       // 3128 B
    P.bucket_start = (int*)(ws + 1576960);       // 3132 B
    P.counter      = (int*)(ws + 1580160);       // 4 B
    P.histT        = (int*)(ws + 1581056);       // 1.6 MB (ends 3.18 MB)
    P.baseT        = (int*)(ws + 3182592);       // 1.6 MB (ends 4.78 MB)
    P.srt          = (int*)(ws + 4784128);       // 6.4 MB (ends 11.18 MB)
    P.bufA         = (unsigned*)(ws + 11184128); // 12.8 MB bf16 hh1 (ends 23.98 MB)
    P.bufC         = (unsigned*)(ws + 23984128); // 12.8 MB bf16 hh2 (ends 36.78 MB)
    P.pairs        = (int*)(ws + 36784128);      // 6.4 MB (ends 43.18 MB)
    P.Wp1          = (unsigned short*)(ws + 43200000);  // 8 KB
    P.Wp2          = (unsigned short*)(ws + 43216384);  // 8 KB

    void* args[] = { &P };
    hipError_t err = hipLaunchCooperativeKernel((const void*)gcn_mega,
                                                dim3(NGRID), dim3(256), args, 0, stream);
    if (err != hipSuccess) {
        // fallback: identical phases as 6 stream-ordered launches
        k_hist<<<NGRID, 256, 0, stream>>>(P);
        k_colscan<<<NGRID, 256, 0, stream>>>(P);
        k_scatter<<<NGRID, 256, 0, stream>>>(P);
        k_place<<<NGRID, 256, 0, stream>>>(P);
        k_agg1<<<NGRID, 256, 0, stream>>>(P);
        k_agg2<<<NGRID, 256, 0, stream>>>(P);
    }
}

// Round 11
// 223.376 us; speedup vs baseline: 2.8673x; 2.8673x over previous
//
#include <hip/hip_runtime.h>

#define NN 100000
#define NE 1600000
#define NPB 128                       // nodes per coarse bucket (node>>7)
#define NBUCK ((NN + NPB - 1) / NPB)  // 782
#define NSB 512                       // scatter blocks / hist chunks
#define ESB (NE / NSB)                // 3125 edges per chunk
#define PCAP 3072                     // LDS staging cap in place_deg (bucket avg ~2046)
// IN_C = HID_C = 64, OUT_C = 16

typedef __bf16 v8bf __attribute__((ext_vector_type(8)));
typedef float  v4f  __attribute__((ext_vector_type(4)));

union Frag { v8bf v; uint4 u; unsigned short s[8]; };

// fp32 -> bf16 (round-to-nearest-even), returns low 16 bits
__device__ inline unsigned f2bf(float f) {
    unsigned u = __float_as_uint(f);
    return (u + 0x7fffu + ((u >> 16) & 1u)) >> 16;
}

// 4 packed bf16 (uint2) -> float4
__device__ inline float4 bf4_to_f4(uint2 u) {
    float4 r;
    r.x = __uint_as_float(u.x << 16);
    r.y = __uint_as_float(u.x & 0xffff0000u);
    r.z = __uint_as_float(u.y << 16);
    r.w = __uint_as_float(u.y & 0xffff0000u);
    return r;
}

// ---------------- B: hist (512 blocks) ∥ wpack (2) ∥ counter init (1) --------
__global__ void hist_prep_kernel(const int* __restrict__ dst, int* __restrict__ histT,
                                 const float* __restrict__ W1, const float* __restrict__ W2,
                                 unsigned short* __restrict__ Wp1,
                                 unsigned short* __restrict__ Wp2,
                                 int* __restrict__ counter) {
    __shared__ int lhist[NBUCK];
    int t = threadIdx.x;
    int b = blockIdx.x;
    if (b >= NSB) {
        int w = b - NSB;
        if (w == 2) { if (t == 0) atomicExch(counter, 0); return; }
        const float* W = w ? W2 : W1;
        unsigned short* Wp = w ? Wp2 : Wp1;
        for (int idx = t; idx < 4096; idx += 256) {
            int j = idx & 7, n = (idx >> 3) & 15, f = idx >> 7;
            int q = f & 3, s = (f >> 2) & 1, c = f >> 3;
            Wp[idx] = (unsigned short)f2bf(W[(32 * s + 8 * q + j) * 64 + 16 * c + n]);
        }
        return;
    }
    for (int i = t; i < NBUCK; i += 256) lhist[i] = 0;
    __syncthreads();
    int start = b * ESB, end = start + ESB;
    for (int e = start + t; e < end; e += 256)
        atomicAdd(&lhist[dst[e] >> 7], 1);
    __syncthreads();
    for (int i = t; i < NBUCK; i += 256)
        histT[i * NSB + b] = lhist[i];   // transposed: bucket-major
}

// ---------------- C: per-bucket colscan + last-block bscan -------------------
__global__ void colscan_bscan_kernel(const int* __restrict__ histT, int* __restrict__ baseT,
                                     int* __restrict__ btot, int* __restrict__ bucket_start,
                                     int* __restrict__ counter) {
    __shared__ int sd[256];
    __shared__ int isLast;
    int k = blockIdx.x, t = threadIdx.x;
    const int* col = histT + k * NSB;
    int a0 = col[2 * t], a1 = col[2 * t + 1];
    int my = a0 + a1;
    sd[t] = my;
    __syncthreads();
    #pragma unroll
    for (int off = 1; off < 256; off <<= 1) {
        int v = (t >= off) ? sd[t - off] : 0;
        __syncthreads();
        sd[t] += v;
        __syncthreads();
    }
    int excl = sd[t] - my;
    baseT[k * NSB + 2 * t]     = excl;
    baseT[k * NSB + 2 * t + 1] = excl + a0;
    if (t == 255) atomicExch(&btot[k], sd[255]);     // device-scope publish
    __syncthreads();                                 // exch drained before barrier
    if (t == 0) isLast = (atomicAdd(counter, 1) == NBUCK - 1);
    __syncthreads();
    if (!isLast) return;
    // ---- bscan, executed by the last-arriving block ----
    __threadfence();
    int base = t * 4;
    int d0 = (base + 0 < NBUCK) ? atomicAdd(&btot[base + 0], 0) : 0;
    int d1 = (base + 1 < NBUCK) ? atomicAdd(&btot[base + 1], 0) : 0;
    int d2 = (base + 2 < NBUCK) ? atomicAdd(&btot[base + 2], 0) : 0;
    int d3 = (base + 3 < NBUCK) ? atomicAdd(&btot[base + 3], 0) : 0;
    int m2 = d0 + d1 + d2 + d3;
    __syncthreads();           // sd reuse
    sd[t] = m2;
    __syncthreads();
    #pragma unroll
    for (int off = 1; off < 256; off <<= 1) {
        int v = (t >= off) ? sd[t - off] : 0;
        __syncthreads();
        sd[t] += v;
        __syncthreads();
    }
    int ex2 = sd[t] - m2;
    if (base + 0 < NBUCK) bucket_start[base + 0] = ex2;
    if (base + 1 < NBUCK) bucket_start[base + 1] = ex2 + d0;
    if (base + 2 < NBUCK) bucket_start[base + 2] = ex2 + d0 + d1;
    if (base + 3 < NBUCK) bucket_start[base + 3] = ex2 + d0 + d1 + d2;
    if (t == 255) bucket_start[NBUCK] = sd[255];   // == NE
}

// ---------------- D: stable bucket scatter, packed payload -------------------
// pack = (dst & 127) << 20 | src   (src < 2^20, loc < 2^7)
__global__ void scatter2_kernel(const int* __restrict__ src, const int* __restrict__ dst,
                                const int* __restrict__ baseT,
                                const int* __restrict__ bucket_start,
                                int* __restrict__ pairs) {
    __shared__ int lcur[NBUCK];
    int t = threadIdx.x, b = blockIdx.x;
    for (int i = t; i < NBUCK; i += 256)
        lcur[i] = bucket_start[i] + baseT[i * NSB + b];
    __syncthreads();
    int start = b * ESB, end = start + ESB;
    for (int e = start + t; e < end; e += 256) {
        int d = dst[e];
        int pos = atomicAdd(&lcur[d >> 7], 1);
        pairs[pos] = ((d & 127) << 20) | src[e];
    }
}

// ---------------- E: per-bucket deg/dinv/row_start + CSR placement ----------
__global__ void place_deg_kernel(const int* __restrict__ bucket_start,
                                 const int* __restrict__ pairs,
                                 int* __restrict__ deg, float* __restrict__ dinv,
                                 int* __restrict__ row_start,
                                 int* __restrict__ sorted_src) {
    __shared__ int lp[PCAP];
    __shared__ int lcnt[NPB];
    __shared__ int loff[NPB];
    __shared__ int lpos[NPB];
    __shared__ int sd[NPB];
    int k = blockIdx.x, t = threadIdx.x;
    int node0 = k * NPB;
    if (t < NPB) { lcnt[t] = 0; lpos[t] = 0; }
    __syncthreads();
    int bs = bucket_start[k], be = bucket_start[k + 1];
    int n = be - bs;
    for (int pos = t; pos < n; pos += 256) {
        int p = pairs[bs + pos];
        if (pos < PCAP) lp[pos] = p;
        atomicAdd(&lcnt[p >> 20], 1);
    }
    __syncthreads();
    int my = (t < NPB) ? lcnt[t] : 0;
    if (t < NPB) sd[t] = my;
    __syncthreads();
    #pragma unroll
    for (int off = 1; off < NPB; off <<= 1) {
        int v = (t < NPB && t >= off) ? sd[t - off] : 0;
        __syncthreads();
        if (t < NPB) sd[t] += v;
        __syncthreads();
    }
    if (t < NPB) {
        int excl = sd[t] - my;
        loff[t] = excl;
        int nd = node0 + t;
        if (nd < NN) {
            deg[nd] = my;
            dinv[nd] = rsqrtf((float)(my + 1));
            row_start[nd] = bs + excl;
        }
    }
    __syncthreads();
    for (int pos = t; pos < n; pos += 256) {
        int p = (pos < PCAP) ? lp[pos] : pairs[bs + pos];
        int loc = p >> 20;
        int off = atomicAdd(&lpos[loc], 1);
        sorted_src[bs + loff[loc] + off] = p & 0xFFFFF;
    }
}

// ---------------- gemm layer 1: fp32 input, bf16 output, MFMA ----------------
__global__ void gemm_mfma_f32_kernel(const float* __restrict__ in,
                                     const unsigned short* __restrict__ Wp,
                                     const float* __restrict__ dinv,
                                     unsigned* __restrict__ out) {
    int lane = threadIdx.x & 63;
    int wv = threadIdx.x >> 6;
    int node0 = blockIdx.x * 64 + wv * 16;
    int m = lane & 15, quad = lane >> 4;
    int node = node0 + m;
    int lnode = (node < NN) ? node : NN - 1;

    Frag a[2];
    const float* xr = in + lnode * 64 + quad * 8;
    #pragma unroll
    for (int s = 0; s < 2; ++s) {
        float4 f0 = *(const float4*)(xr + s * 32);
        float4 f1 = *(const float4*)(xr + s * 32 + 4);
        a[s].s[0] = (unsigned short)f2bf(f0.x);
        a[s].s[1] = (unsigned short)f2bf(f0.y);
        a[s].s[2] = (unsigned short)f2bf(f0.z);
        a[s].s[3] = (unsigned short)f2bf(f0.w);
        a[s].s[4] = (unsigned short)f2bf(f1.x);
        a[s].s[5] = (unsigned short)f2bf(f1.y);
        a[s].s[6] = (unsigned short)f2bf(f1.z);
        a[s].s[7] = (unsigned short)f2bf(f1.w);
    }
    Frag b[8];
    #pragma unroll
    for (int cs = 0; cs < 8; ++cs)
        b[cs].u = *(const uint4*)(Wp + ((cs * 4 + quad) * 16 + m) * 8);

    v4f acc[4] = {};
    #pragma unroll
    for (int c = 0; c < 4; ++c) {
        acc[c] = __builtin_amdgcn_mfma_f32_16x16x32_bf16(a[0].v, b[c * 2 + 0].v, acc[c], 0, 0, 0);
        acc[c] = __builtin_amdgcn_mfma_f32_16x16x32_bf16(a[1].v, b[c * 2 + 1].v, acc[c], 0, 0, 0);
    }
    #pragma unroll
    for (int r = 0; r < 4; ++r) {
        int onode = node0 + quad * 4 + r;
        float di = dinv[(onode < NN) ? onode : NN - 1];
        #pragma unroll
        for (int c = 0; c < 4; ++c) {
            float v = acc[c][r] * di;
            float p = __shfl_xor(v, 1);
            if (!(lane & 1) && onode < NN) {
                unsigned pk = f2bf(v) | (f2bf(p) << 16);
                out[onode * 32 + c * 8 + (m >> 1)] = pk;
            }
        }
    }
}

// ---------------- shared gather core (proven 8/4/1 ladder) -------------------
__device__ inline float4 gather_row(const int* __restrict__ row_start,
                                    const int* __restrict__ deg,
                                    const int* __restrict__ sorted_src,
                                    const uint2* __restrict__ hb,
                                    const float* __restrict__ dinv,
                                    const float* __restrict__ b,
                                    int node, int q) {
    int e = row_start[node];
    int end = e + deg[node];
    float4 acc = bf4_to_f4(hb[node * 16 + q]);   // self-loop term
    while (e < end) {
        int take = min(end - e, 16);
        int sidx = (q < take) ? sorted_src[e + q] : 0;
        int j = 0;
        for (; j + 8 <= take; j += 8) {
            int s0 = __shfl(sidx, j + 0, 16);
            int s1 = __shfl(sidx, j + 1, 16);
            int s2 = __shfl(sidx, j + 2, 16);
            int s3 = __shfl(sidx, j + 3, 16);
            int s4 = __shfl(sidx, j + 4, 16);
            int s5 = __shfl(sidx, j + 5, 16);
            int s6 = __shfl(sidx, j + 6, 16);
            int s7 = __shfl(sidx, j + 7, 16);
            uint2 u0 = hb[s0 * 16 + q];
            uint2 u1 = hb[s1 * 16 + q];
            uint2 u2 = hb[s2 * 16 + q];
            uint2 u3 = hb[s3 * 16 + q];
            uint2 u4 = hb[s4 * 16 + q];
            uint2 u5 = hb[s5 * 16 + q];
            uint2 u6 = hb[s6 * 16 + q];
            uint2 u7 = hb[s7 * 16 + q];
            float4 v0 = bf4_to_f4(u0), v1 = bf4_to_f4(u1);
            float4 v2 = bf4_to_f4(u2), v3 = bf4_to_f4(u3);
            float4 v4 = bf4_to_f4(u4), v5 = bf4_to_f4(u5);
            float4 v6 = bf4_to_f4(u6), v7 = bf4_to_f4(u7);
            acc.x += (v0.x + v1.x) + (v2.x + v3.x) + (v4.x + v5.x) + (v6.x + v7.x);
            acc.y += (v0.y + v1.y) + (v2.y + v3.y) + (v4.y + v5.y) + (v6.y + v7.y);
            acc.z += (v0.z + v1.z) + (v2.z + v3.z) + (v4.z + v5.z) + (v6.z + v7.z);
            acc.w += (v0.w + v1.w) + (v2.w + v3.w) + (v4.w + v5.w) + (v6.w + v7.w);
        }
        for (; j + 4 <= take; j += 4) {
            int s0 = __shfl(sidx, j + 0, 16);
            int s1 = __shfl(sidx, j + 1, 16);
            int s2 = __shfl(sidx, j + 2, 16);
            int s3 = __shfl(sidx, j + 3, 16);
            uint2 u0 = hb[s0 * 16 + q];
            uint2 u1 = hb[s1 * 16 + q];
            uint2 u2 = hb[s2 * 16 + q];
            uint2 u3 = hb[s3 * 16 + q];
            float4 v0 = bf4_to_f4(u0), v1 = bf4_to_f4(u1);
            float4 v2 = bf4_to_f4(u2), v3 = bf4_to_f4(u3);
            acc.x += (v0.x + v1.x) + (v2.x + v3.x);
            acc.y += (v0.y + v1.y) + (v2.y + v3.y);
            acc.z += (v0.z + v1.z) + (v2.z + v3.z);
            acc.w += (v0.w + v1.w) + (v2.w + v3.w);
        }
        for (; j < take; ++j) {
            int s0 = __shfl(sidx, j, 16);
            float4 v0 = bf4_to_f4(hb[s0 * 16 + q]);
            acc.x += v0.x; acc.y += v0.y; acc.z += v0.z; acc.w += v0.w;
        }
        e += take;
    }
    float di = dinv[node];
    float4 bb = *(const float4*)(b + q * 4);
    float4 r;
    r.x = fmaxf(fmaf(di, acc.x, bb.x), 0.f);
    r.y = fmaxf(fmaf(di, acc.y, bb.y), 0.f);
    r.z = fmaxf(fmaf(di, acc.z, bb.z), 0.f);
    r.w = fmaxf(fmaf(di, acc.w, bb.w), 0.f);
    return r;
}

// ---------------- F: layer-1 aggregate -> LDS -> layer-2 gemm (MFMA) ---------
__global__ void agg1_gemm2_kernel(const int* __restrict__ row_start,
                                  const int* __restrict__ deg,
                                  const int* __restrict__ sorted_src,
                                  const uint2* __restrict__ hb,    // hh1 bf16 rows
                                  const float* __restrict__ dinv,
                                  const float* __restrict__ b1,
                                  const unsigned short* __restrict__ Wp2,
                                  unsigned* __restrict__ out /* hh2 bf16 rows */) {
    __shared__ unsigned short hsl[64][72];   // 9216 B
    int t = threadIdx.x;
    int lane = t & 63, wv = t >> 6;
    int node0 = blockIdx.x * 64;
    int q = lane & 15;

    #pragma unroll
    for (int r4 = 0; r4 < 4; ++r4) {
        int nl = wv * 16 + r4 * 4 + (lane >> 4);
        int node = node0 + nl;
        int cn = (node < NN) ? node : NN - 1;
        float4 r = gather_row(row_start, deg, sorted_src, hb, dinv, b1, cn, q);
        uint2 pk;
        pk.x = f2bf(r.x) | (f2bf(r.y) << 16);
        pk.y = f2bf(r.z) | (f2bf(r.w) << 16);
        *(uint2*)&hsl[nl][q * 4] = pk;
    }
    __syncthreads();

    int m = lane & 15, quad = lane >> 4;
    Frag b[8];
    #pragma unroll
    for (int cs = 0; cs < 8; ++cs)
        b[cs].u = *(const uint4*)(Wp2 + ((cs * 4 + quad) * 16 + m) * 8);
    Frag a[2];
    #pragma unroll
    for (int s = 0; s < 2; ++s)
        a[s].u = *(const uint4*)&hsl[wv * 16 + m][s * 32 + quad * 8];

    v4f acc[4] = {};
    #pragma unroll
    for (int c = 0; c < 4; ++c) {
        acc[c] = __builtin_amdgcn_mfma_f32_16x16x32_bf16(a[0].v, b[c * 2 + 0].v, acc[c], 0, 0, 0);
        acc[c] = __builtin_amdgcn_mfma_f32_16x16x32_bf16(a[1].v, b[c * 2 + 1].v, acc[c], 0, 0, 0);
    }
    #pragma unroll
    for (int r = 0; r < 4; ++r) {
        int onode = node0 + wv * 16 + quad * 4 + r;
        float di = dinv[(onode < NN) ? onode : NN - 1];
        #pragma unroll
        for (int c = 0; c < 4; ++c) {
            float v = acc[c][r] * di;
            float p = __shfl_xor(v, 1);
            if (!(lane & 1) && onode < NN) {
                unsigned pk = f2bf(v) | (f2bf(p) << 16);
                out[onode * 32 + c * 8 + (m >> 1)] = pk;
            }
        }
    }
}

// ---------------- G: layer-2 aggregate + FC + log_softmax --------------------
__global__ void aggregate2_final_kernel(const int* __restrict__ row_start,
                                        const int* __restrict__ deg,
                                        const int* __restrict__ sorted_src,
                                        const uint2* __restrict__ hb,
                                        const float* __restrict__ dinv,
                                        const float* __restrict__ b,
                                        const float* __restrict__ Wfc,
                                        const float* __restrict__ bfc,
                                        float* __restrict__ out) {
    __shared__ float Ws[64][16];   // 4 KB
    __shared__ float hs[16][68];   // padded
    int t = threadIdx.x;
    #pragma unroll
    for (int k = 0; k < 4; ++k)
        ((float*)Ws)[k * 256 + t] = Wfc[k * 256 + t];

    int node = blockIdx.x * 16 + (t >> 4);
    int q = t & 15;
    float4 r = gather_row(row_start, deg, sorted_src, hb, dinv, b, node, q);
    hs[t >> 4][q * 4 + 0] = r.x;
    hs[t >> 4][q * 4 + 1] = r.y;
    hs[t >> 4][q * 4 + 2] = r.z;
    hs[t >> 4][q * 4 + 3] = r.w;
    __syncthreads();

    int nl = t >> 4;
    int c  = t & 15;
    float acc = bfc[c];
    #pragma unroll
    for (int k = 0; k < 64; ++k)
        acc = fmaf(hs[nl][k], Ws[k][c], acc);
    float m = acc;
    #pragma unroll
    for (int off = 8; off; off >>= 1)
        m = fmaxf(m, __shfl_xor(m, off, 16));
    float ex = __expf(acc - m);
    float s = ex;
    #pragma unroll
    for (int off = 8; off; off >>= 1)
        s += __shfl_xor(s, off, 16);
    out[blockIdx.x * 256 + t] = acc - m - __logf(s);
}

extern "C" void kernel_launch(void* const* d_in, const int* in_sizes, int n_in,
                              void* d_out, int out_size, void* d_ws, size_t ws_size,
                              hipStream_t stream) {
    const float* x   = (const float*)d_in[0];
    const int*   ei  = (const int*)d_in[1];     // [2, E] int32
    const float* W1  = (const float*)d_in[2];
    const float* b1  = (const float*)d_in[3];
    const float* W2  = (const float*)d_in[4];
    const float* b2  = (const float*)d_in[5];
    const float* Wfc = (const float*)d_in[6];
    const float* bfc = (const float*)d_in[7];
    float* out = (float*)d_out;

    char* ws = (char*)d_ws;
    int*      deg          = (int*)(ws + 0);            // 400 KB
    float*    dinv         = (float*)(ws + 524288);     // 400 KB
    int*      row_start    = (int*)(ws + 1048576);      // 400 KB
    int*      btot         = (int*)(ws + 1572864);      // 3128 B
    int*      bucket_start = (int*)(ws + 1576960);      // 3132 B
    int*      counter      = (int*)(ws + 1580160);      // 4 B
    int*      histT        = (int*)(ws + 1581056);      // 1.6 MB (ends 3.18 MB)
    int*      baseT        = (int*)(ws + 3182592);      // 1.6 MB (ends 4.78 MB)
    int*      srt          = (int*)(ws + 4784128);      // 6.4 MB (ends 11.18 MB)
    unsigned* bufA         = (unsigned*)(ws + 11184128);// 12.8 MB bf16 hh1 (ends 23.98 MB)
    unsigned* bufC         = (unsigned*)(ws + 23984128);// 12.8 MB bf16 hh2 (ends 36.78 MB)
    int*      pairs        = (int*)(ws + 36784128);     // 6.4 MB (ends 43.18 MB)
    unsigned short* Wp1    = (unsigned short*)(ws + 43200000);  // 8 KB
    unsigned short* Wp2    = (unsigned short*)(ws + 43216384);  // 8 KB

    const int* src = ei;        // edge_index[0]
    const int* dst = ei + NE;   // edge_index[1]

    // B: histogram ∥ weight-pack ∥ ticket-counter init
    hist_prep_kernel<<<NSB + 3, 256, 0, stream>>>(dst, histT, W1, W2, Wp1, Wp2, counter);

    // C: per-bucket scan of block counts; last block scans bucket totals
    colscan_bscan_kernel<<<NBUCK, 256, 0, stream>>>(histT, baseT, btot, bucket_start, counter);

    // D: stable bucket scatter (packed payload, no global atomics)
    scatter2_kernel<<<NSB, 256, 0, stream>>>(src, dst, baseT, bucket_start, pairs);

    // E: deg/dinv/row_start + exact CSR placement
    place_deg_kernel<<<NBUCK, 256, 0, stream>>>(bucket_start, pairs, deg, dinv, row_start, srt);

    // layer-1 gemm (MFMA)
    gemm_mfma_f32_kernel<<<(NN + 63) / 64, 256, 0, stream>>>(x, Wp1, dinv, bufA);

    // F: layer-1 aggregate + layer-2 gemm (fused)
    agg1_gemm2_kernel<<<(NN + 63) / 64, 256, 0, stream>>>(row_start, deg, srt,
        (const uint2*)bufA, dinv, b1, Wp2, bufC);

    // G: layer-2 aggregate + FC + log_softmax (fused)
    aggregate2_final_kernel<<<NN * 16 / 256, 256, 0, stream>>>(row_start, deg, srt,
        (const uint2*)bufC, dinv, b2, Wfc, bfc, out);
}

// Round 12
// 214.363 us; speedup vs baseline: 2.9879x; 1.0420x over previous
//
#include <hip/hip_runtime.h>

#define NN 100000
#define NE 1600000
#define NPB 128                       // nodes per coarse bucket (node>>7)
#define NBUCK ((NN + NPB - 1) / NPB)  // 782
#define NSB 512                       // scatter blocks
#define ESB (NE / NSB)                // 3125 edges per scatter block
#define PCAP 3072                     // LDS staging cap in place_deg (bucket avg ~2046)
// IN_C = HID_C = 64, OUT_C = 16

typedef __bf16 v8bf __attribute__((ext_vector_type(8)));
typedef float  v4f  __attribute__((ext_vector_type(4)));

union Frag { v8bf v; uint4 u; unsigned short s[8]; };

// fp32 -> bf16 (round-to-nearest-even), returns low 16 bits
__device__ inline unsigned f2bf(float f) {
    unsigned u = __float_as_uint(f);
    return (u + 0x7fffu + ((u >> 16) & 1u)) >> 16;
}

// 4 packed bf16 (uint2) -> float4
__device__ inline float4 bf4_to_f4(uint2 u) {
    float4 r;
    r.x = __uint_as_float(u.x << 16);
    r.y = __uint_as_float(u.x & 0xffff0000u);
    r.z = __uint_as_float(u.y << 16);
    r.w = __uint_as_float(u.y & 0xffff0000u);
    return r;
}

// ---------------- S0: per-block coarse bucket histogram ----------------
__global__ void hist_kernel(const int* __restrict__ dst, int* __restrict__ histT) {
    __shared__ int lhist[NBUCK];
    int t = threadIdx.x;
    for (int i = t; i < NBUCK; i += 256) lhist[i] = 0;
    __syncthreads();
    int start = blockIdx.x * ESB, end = start + ESB;
    for (int e = start + t; e < end; e += 256)
        atomicAdd(&lhist[dst[e] >> 7], 1);
    __syncthreads();
    for (int i = t; i < NBUCK; i += 256)
        histT[i * NSB + blockIdx.x] = lhist[i];   // transposed: bucket-major
}

// ---------------- S1: per-bucket scan of 512 block counts ----------------
__global__ void colscan_kernel(const int* __restrict__ histT, int* __restrict__ baseT,
                               int* __restrict__ btot) {
    __shared__ int sd[256];
    int k = blockIdx.x, t = threadIdx.x;
    const int* col = histT + k * NSB;
    int a0 = col[2 * t], a1 = col[2 * t + 1];
    int my = a0 + a1;
    sd[t] = my;
    __syncthreads();
    #pragma unroll
    for (int off = 1; off < 256; off <<= 1) {
        int v = (t >= off) ? sd[t - off] : 0;
        __syncthreads();
        sd[t] += v;
        __syncthreads();
    }
    int excl = sd[t] - my;
    baseT[k * NSB + 2 * t]     = excl;
    baseT[k * NSB + 2 * t + 1] = excl + a0;
    if (t == 255) btot[k] = sd[255];
}

// ---------------- S2: scan bucket totals -> bucket_start[NBUCK+1] ----------------
__global__ void bscan_kernel(const int* __restrict__ btot, int* __restrict__ bucket_start) {
    __shared__ int sd[256];
    int t = threadIdx.x;
    int base = t * 4;
    int d0 = (base + 0 < NBUCK) ? btot[base + 0] : 0;
    int d1 = (base + 1 < NBUCK) ? btot[base + 1] : 0;
    int d2 = (base + 2 < NBUCK) ? btot[base + 2] : 0;
    int d3 = (base + 3 < NBUCK) ? btot[base + 3] : 0;
    int my = d0 + d1 + d2 + d3;
    sd[t] = my;
    __syncthreads();
    #pragma unroll
    for (int off = 1; off < 256; off <<= 1) {
        int v = (t >= off) ? sd[t - off] : 0;
        __syncthreads();
        sd[t] += v;
        __syncthreads();
    }
    int excl = sd[t] - my;
    if (base + 0 < NBUCK) bucket_start[base + 0] = excl;
    if (base + 1 < NBUCK) bucket_start[base + 1] = excl + d0;
    if (base + 2 < NBUCK) bucket_start[base + 2] = excl + d0 + d1;
    if (base + 3 < NBUCK) bucket_start[base + 3] = excl + d0 + d1 + d2;
    if (t == 255) bucket_start[NBUCK] = sd[255];   // == NE
}

// ---------------- S3: stable bucket scatter, packed payload ----------------
// pack = (dst & 127) << 20 | src   (src < 2^20, loc < 2^7)
__global__ void scatter2_kernel(const int* __restrict__ src, const int* __restrict__ dst,
                                const int* __restrict__ baseT,
                                const int* __restrict__ bucket_start,
                                int* __restrict__ pairs) {
    __shared__ int lcur[NBUCK];
    int t = threadIdx.x, b = blockIdx.x;
    for (int i = t; i < NBUCK; i += 256)
        lcur[i] = bucket_start[i] + baseT[i * NSB + b];
    __syncthreads();
    int start = b * ESB, end = start + ESB;
    for (int e = start + t; e < end; e += 256) {
        int d = dst[e];
        int pos = atomicAdd(&lcur[d >> 7], 1);
        pairs[pos] = ((d & 127) << 20) | src[e];
    }
}

// ---------------- S4: per-bucket deg/dinv/row_start + CSR placement ----------
// Single global read of pairs: staged in LDS (fallback to global past PCAP).
__global__ void place_deg_kernel(const int* __restrict__ bucket_start,
                                 const int* __restrict__ pairs,
                                 int* __restrict__ deg, float* __restrict__ dinv,
                                 int* __restrict__ row_start,
                                 int* __restrict__ sorted_src) {
    __shared__ int lp[PCAP];
    __shared__ int lcnt[NPB];
    __shared__ int loff[NPB];
    __shared__ int lpos[NPB];
    __shared__ int sd[NPB];
    int k = blockIdx.x, t = threadIdx.x;
    int node0 = k * NPB;
    if (t < NPB) { lcnt[t] = 0; lpos[t] = 0; }
    __syncthreads();
    int bs = bucket_start[k], be = bucket_start[k + 1];
    int n = be - bs;
    for (int pos = t; pos < n; pos += 256) {
        int p = pairs[bs + pos];
        if (pos < PCAP) lp[pos] = p;
        atomicAdd(&lcnt[p >> 20], 1);
    }
    __syncthreads();
    int my = (t < NPB) ? lcnt[t] : 0;
    if (t < NPB) sd[t] = my;
    __syncthreads();
    #pragma unroll
    for (int off = 1; off < NPB; off <<= 1) {
        int v = (t < NPB && t >= off) ? sd[t - off] : 0;
        __syncthreads();
        if (t < NPB) sd[t] += v;
        __syncthreads();
    }
    if (t < NPB) {
        int excl = sd[t] - my;
        loff[t] = excl;
        int nd = node0 + t;
        if (nd < NN) {
            deg[nd] = my;
            dinv[nd] = rsqrtf((float)(my + 1));
            row_start[nd] = bs + excl;
        }
    }
    __syncthreads();
    for (int pos = t; pos < n; pos += 256) {
        int p = (pos < PCAP) ? lp[pos] : pairs[bs + pos];
        int loc = p >> 20;
        int off = atomicAdd(&lpos[loc], 1);
        sorted_src[bs + loff[loc] + off] = p & 0xFFFFF;
    }
}

// ---------------- W pack: fp32 64x64 -> bf16 B-fragments ----------------
__global__ void wpack_kernel(const float* __restrict__ W1, const float* __restrict__ W2,
                             unsigned short* __restrict__ Wp1, unsigned short* __restrict__ Wp2) {
    const float* W = blockIdx.x ? W2 : W1;
    unsigned short* Wp = blockIdx.x ? Wp2 : Wp1;
    int t = threadIdx.x;
    for (int idx = t; idx < 4096; idx += 256) {
        int j = idx & 7;
        int n = (idx >> 3) & 15;
        int f = idx >> 7;          // 0..31
        int q = f & 3;
        int s = (f >> 2) & 1;
        int c = f >> 3;
        int k = 32 * s + 8 * q + j;
        int col = 16 * c + n;
        Wp[idx] = (unsigned short)f2bf(W[k * 64 + col]);
    }
}

// ---------------- gemm layer 1: fp32 input, bf16 output, MFMA ----------------
__global__ void gemm_mfma_f32_kernel(const float* __restrict__ in,
                                     const unsigned short* __restrict__ Wp,
                                     const float* __restrict__ dinv,
                                     unsigned* __restrict__ out) {
    int lane = threadIdx.x & 63;
    int wv = threadIdx.x >> 6;
    int node0 = blockIdx.x * 64 + wv * 16;
    int m = lane & 15, quad = lane >> 4;
    int node = node0 + m;
    int lnode = (node < NN) ? node : NN - 1;

    Frag a[2];
    const float* xr = in + lnode * 64 + quad * 8;
    #pragma unroll
    for (int s = 0; s < 2; ++s) {
        float4 f0 = *(const float4*)(xr + s * 32);
        float4 f1 = *(const float4*)(xr + s * 32 + 4);
        a[s].s[0] = (unsigned short)f2bf(f0.x);
        a[s].s[1] = (unsigned short)f2bf(f0.y);
        a[s].s[2] = (unsigned short)f2bf(f0.z);
        a[s].s[3] = (unsigned short)f2bf(f0.w);
        a[s].s[4] = (unsigned short)f2bf(f1.x);
        a[s].s[5] = (unsigned short)f2bf(f1.y);
        a[s].s[6] = (unsigned short)f2bf(f1.z);
        a[s].s[7] = (unsigned short)f2bf(f1.w);
    }
    Frag b[8];
    #pragma unroll
    for (int cs = 0; cs < 8; ++cs)
        b[cs].u = *(const uint4*)(Wp + ((cs * 4 + quad) * 16 + m) * 8);

    v4f acc[4] = {};
    #pragma unroll
    for (int c = 0; c < 4; ++c) {
        acc[c] = __builtin_amdgcn_mfma_f32_16x16x32_bf16(a[0].v, b[c * 2 + 0].v, acc[c], 0, 0, 0);
        acc[c] = __builtin_amdgcn_mfma_f32_16x16x32_bf16(a[1].v, b[c * 2 + 1].v, acc[c], 0, 0, 0);
    }
    #pragma unroll
    for (int r = 0; r < 4; ++r) {
        int onode = node0 + quad * 4 + r;
        float di = dinv[(onode < NN) ? onode : NN - 1];
        #pragma unroll
        for (int c = 0; c < 4; ++c) {
            float v = acc[c][r] * di;
            float p = __shfl_xor(v, 1);
            if (!(lane & 1) && onode < NN) {
                unsigned pk = f2bf(v) | (f2bf(p) << 16);
                out[onode * 32 + c * 8 + (m >> 1)] = pk;
            }
        }
    }
}

// ---------------- shared gather core (8/4/1 ladder) --------------------------
__device__ inline float4 gather_row(const int* __restrict__ row_start,
                                    const int* __restrict__ deg,
                                    const int* __restrict__ sorted_src,
                                    const uint2* __restrict__ hb,
                                    const float* __restrict__ dinv,
                                    const float* __restrict__ b,
                                    int node, int q) {
    int e = row_start[node];
    int end = e + deg[node];
    float4 acc = bf4_to_f4(hb[node * 16 + q]);   // self-loop term
    while (e < end) {
        int take = min(end - e, 16);
        int sidx = (q < take) ? sorted_src[e + q] : 0;
        int j = 0;
        for (; j + 8 <= take; j += 8) {
            int s0 = __shfl(sidx, j + 0, 16);
            int s1 = __shfl(sidx, j + 1, 16);
            int s2 = __shfl(sidx, j + 2, 16);
            int s3 = __shfl(sidx, j + 3, 16);
            int s4 = __shfl(sidx, j + 4, 16);
            int s5 = __shfl(sidx, j + 5, 16);
            int s6 = __shfl(sidx, j + 6, 16);
            int s7 = __shfl(sidx, j + 7, 16);
            uint2 u0 = hb[s0 * 16 + q];
            uint2 u1 = hb[s1 * 16 + q];
            uint2 u2 = hb[s2 * 16 + q];
            uint2 u3 = hb[s3 * 16 + q];
            uint2 u4 = hb[s4 * 16 + q];
            uint2 u5 = hb[s5 * 16 + q];
            uint2 u6 = hb[s6 * 16 + q];
            uint2 u7 = hb[s7 * 16 + q];
            float4 v0 = bf4_to_f4(u0), v1 = bf4_to_f4(u1);
            float4 v2 = bf4_to_f4(u2), v3 = bf4_to_f4(u3);
            float4 v4 = bf4_to_f4(u4), v5 = bf4_to_f4(u5);
            float4 v6 = bf4_to_f4(u6), v7 = bf4_to_f4(u7);
            acc.x += (v0.x + v1.x) + (v2.x + v3.x) + (v4.x + v5.x) + (v6.x + v7.x);
            acc.y += (v0.y + v1.y) + (v2.y + v3.y) + (v4.y + v5.y) + (v6.y + v7.y);
            acc.z += (v0.z + v1.z) + (v2.z + v3.z) + (v4.z + v5.z) + (v6.z + v7.z);
            acc.w += (v0.w + v1.w) + (v2.w + v3.w) + (v4.w + v5.w) + (v6.w + v7.w);
        }
        for (; j + 4 <= take; j += 4) {
            int s0 = __shfl(sidx, j + 0, 16);
            int s1 = __shfl(sidx, j + 1, 16);
            int s2 = __shfl(sidx, j + 2, 16);
            int s3 = __shfl(sidx, j + 3, 16);
            uint2 u0 = hb[s0 * 16 + q];
            uint2 u1 = hb[s1 * 16 + q];
            uint2 u2 = hb[s2 * 16 + q];
            uint2 u3 = hb[s3 * 16 + q];
            float4 v0 = bf4_to_f4(u0), v1 = bf4_to_f4(u1);
            float4 v2 = bf4_to_f4(u2), v3 = bf4_to_f4(u3);
            acc.x += (v0.x + v1.x) + (v2.x + v3.x);
            acc.y += (v0.y + v1.y) + (v2.y + v3.y);
            acc.z += (v0.z + v1.z) + (v2.z + v3.z);
            acc.w += (v0.w + v1.w) + (v2.w + v3.w);
        }
        for (; j < take; ++j) {
            int s0 = __shfl(sidx, j, 16);
            float4 v0 = bf4_to_f4(hb[s0 * 16 + q]);
            acc.x += v0.x; acc.y += v0.y; acc.z += v0.z; acc.w += v0.w;
        }
        e += take;
    }
    float di = dinv[node];
    float4 bb = *(const float4*)(b + q * 4);
    float4 r;
    r.x = fmaxf(fmaf(di, acc.x, bb.x), 0.f);
    r.y = fmaxf(fmaf(di, acc.y, bb.y), 0.f);
    r.z = fmaxf(fmaf(di, acc.z, bb.z), 0.f);
    r.w = fmaxf(fmaf(di, acc.w, bb.w), 0.f);
    return r;
}

// ---------------- F: layer-1 aggregate -> LDS -> layer-2 gemm (MFMA) ---------
__global__ void agg1_gemm2_kernel(const int* __restrict__ row_start,
                                  const int* __restrict__ deg,
                                  const int* __restrict__ sorted_src,
                                  const uint2* __restrict__ hb,    // hh1 bf16 rows
                                  const float* __restrict__ dinv,
                                  const float* __restrict__ b1,
                                  const unsigned short* __restrict__ Wp2,
                                  unsigned* __restrict__ out /* hh2 bf16 rows */) {
    __shared__ unsigned short hsl[64][72];   // 9216 B
    int t = threadIdx.x;
    int lane = t & 63, wv = t >> 6;
    int node0 = blockIdx.x * 64;
    int q = lane & 15;

    #pragma unroll
    for (int r4 = 0; r4 < 4; ++r4) {
        int nl = wv * 16 + r4 * 4 + (lane >> 4);
        int node = node0 + nl;
        int cn = (node < NN) ? node : NN - 1;
        float4 r = gather_row(row_start, deg, sorted_src, hb, dinv, b1, cn, q);
        uint2 pk;
        pk.x = f2bf(r.x) | (f2bf(r.y) << 16);
        pk.y = f2bf(r.z) | (f2bf(r.w) << 16);
        *(uint2*)&hsl[nl][q * 4] = pk;
    }
    __syncthreads();

    int m = lane & 15, quad = lane >> 4;
    Frag b[8];
    #pragma unroll
    for (int cs = 0; cs < 8; ++cs)
        b[cs].u = *(const uint4*)(Wp2 + ((cs * 4 + quad) * 16 + m) * 8);
    Frag a[2];
    #pragma unroll
    for (int s = 0; s < 2; ++s)
        a[s].u = *(const uint4*)&hsl[wv * 16 + m][s * 32 + quad * 8];

    v4f acc[4] = {};
    #pragma unroll
    for (int c = 0; c < 4; ++c) {
        acc[c] = __builtin_amdgcn_mfma_f32_16x16x32_bf16(a[0].v, b[c * 2 + 0].v, acc[c], 0, 0, 0);
        acc[c] = __builtin_amdgcn_mfma_f32_16x16x32_bf16(a[1].v, b[c * 2 + 1].v, acc[c], 0, 0, 0);
    }
    #pragma unroll
    for (int r = 0; r < 4; ++r) {
        int onode = node0 + wv * 16 + quad * 4 + r;
        float di = dinv[(onode < NN) ? onode : NN - 1];
        #pragma unroll
        for (int c = 0; c < 4; ++c) {
            float v = acc[c][r] * di;
            float p = __shfl_xor(v, 1);
            if (!(lane & 1) && onode < NN) {
                unsigned pk = f2bf(v) | (f2bf(p) << 16);
                out[onode * 32 + c * 8 + (m >> 1)] = pk;
            }
        }
    }
}

// ---------------- G: layer-2 aggregate fused with FC + log_softmax -----------
__global__ void aggregate2_final_kernel(const int* __restrict__ row_start,
                                        const int* __restrict__ deg,
                                        const int* __restrict__ sorted_src,
                                        const uint2* __restrict__ hb,
                                        const float* __restrict__ dinv,
                                        const float* __restrict__ b,
                                        const float* __restrict__ Wfc,
                                        const float* __restrict__ bfc,
                                        float* __restrict__ out) {
    __shared__ float Ws[64][16];   // 4 KB
    __shared__ float hs[16][68];   // padded
    int t = threadIdx.x;
    #pragma unroll
    for (int k = 0; k < 4; ++k)
        ((float*)Ws)[k * 256 + t] = Wfc[k * 256 + t];

    int node = blockIdx.x * 16 + (t >> 4);
    int q = t & 15;
    float4 r = gather_row(row_start, deg, sorted_src, hb, dinv, b, node, q);
    hs[t >> 4][q * 4 + 0] = r.x;
    hs[t >> 4][q * 4 + 1] = r.y;
    hs[t >> 4][q * 4 + 2] = r.z;
    hs[t >> 4][q * 4 + 3] = r.w;
    __syncthreads();

    int nl = t >> 4;
    int c  = t & 15;
    float acc = bfc[c];
    #pragma unroll
    for (int k = 0; k < 64; ++k)
        acc = fmaf(hs[nl][k], Ws[k][c], acc);
    float m = acc;
    #pragma unroll
    for (int off = 8; off; off >>= 1)
        m = fmaxf(m, __shfl_xor(m, off, 16));
    float ex = __expf(acc - m);
    float s = ex;
    #pragma unroll
    for (int off = 8; off; off >>= 1)
        s += __shfl_xor(s, off, 16);
    out[blockIdx.x * 256 + t] = acc - m - __logf(s);
}

extern "C" void kernel_launch(void* const* d_in, const int* in_sizes, int n_in,
                              void* d_out, int out_size, void* d_ws, size_t ws_size,
                              hipStream_t stream) {
    const float* x   = (const float*)d_in[0];
    const int*   ei  = (const int*)d_in[1];     // [2, E] int32
    const float* W1  = (const float*)d_in[2];
    const float* b1  = (const float*)d_in[3];
    const float* W2  = (const float*)d_in[4];
    const float* b2  = (const float*)d_in[5];
    const float* Wfc = (const float*)d_in[6];
    const float* bfc = (const float*)d_in[7];
    float* out = (float*)d_out;

    char* ws = (char*)d_ws;
    int*      deg          = (int*)(ws + 0);            // 400 KB
    float*    dinv         = (float*)(ws + 524288);     // 400 KB
    int*      row_start    = (int*)(ws + 1048576);      // 400 KB
    int*      btot         = (int*)(ws + 1572864);      // 3128 B
    int*      bucket_start = (int*)(ws + 1576960);      // 3132 B
    int*      histT        = (int*)(ws + 1581056);      // 1.6 MB (ends 3.18 MB)
    int*      baseT        = (int*)(ws + 3182592);      // 1.6 MB (ends 4.78 MB)
    int*      srt          = (int*)(ws + 4784128);      // 6.4 MB (ends 11.18 MB)
    unsigned* bufA         = (unsigned*)(ws + 11184128);// 12.8 MB bf16 hh1 (ends 23.98 MB)
    unsigned* bufC         = (unsigned*)(ws + 23984128);// 12.8 MB bf16 hh2 (ends 36.78 MB)
    int*      pairs        = (int*)(ws + 36784128);     // 6.4 MB (ends 43.18 MB)
    unsigned short* Wp1    = (unsigned short*)(ws + 43200000);  // 8 KB
    unsigned short* Wp2    = (unsigned short*)(ws + 43216384);  // 8 KB

    const int* src = ei;        // edge_index[0]
    const int* dst = ei + NE;   // edge_index[1]

    // ---- weight pack (both layers) ----
    wpack_kernel<<<2, 256, 0, stream>>>(W1, W2, Wp1, Wp2);

    // ---- CSR build (deterministic two-level counting sort; no global atomics) ----
    hist_kernel<<<NSB, 256, 0, stream>>>(dst, histT);
    colscan_kernel<<<NBUCK, 256, 0, stream>>>(histT, baseT, btot);
    bscan_kernel<<<1, 256, 0, stream>>>(btot, bucket_start);
    scatter2_kernel<<<NSB, 256, 0, stream>>>(src, dst, baseT, bucket_start, pairs);
    place_deg_kernel<<<NBUCK, 256, 0, stream>>>(bucket_start, pairs, deg, dinv, row_start, srt);

    // ---- layer 1 gemm (MFMA) ----
    gemm_mfma_f32_kernel<<<(NN + 63) / 64, 256, 0, stream>>>(x, Wp1, dinv, bufA);

    // ---- layer 1 aggregate + layer 2 gemm (fused) ----
    agg1_gemm2_kernel<<<(NN + 63) / 64, 256, 0, stream>>>(row_start, deg, srt,
        (const uint2*)bufA, dinv, b1, Wp2, bufC);

    // ---- layer 2 aggregate + FC + log_softmax (fused) ----
    aggregate2_final_kernel<<<NN * 16 / 256, 256, 0, stream>>>(row_start, deg, srt,
        (const uint2*)bufC, dinv, b2, Wfc, bfc, out);
}